// Round 3
// baseline (125.869 us; speedup 1.0000x reference)
//
#include <hip/hip_runtime.h>
#include <hip/hip_bf16.h>
#include <stdint.h>

// RNDiscriminator: B=64, d^2=64 positions, 26 features, g: 52->256->256, f: 256->1
// h1[i,j] = relu(u'[j] + v[i]); dominant cost sum_ij relu(h1 @ W2 + b2) = 34.4 GF bf16.
//
// k3 structure: W2 staged ONCE per block in LDS, fragment-major (conflict-free
// b128 reads). A-fragments built in registers from u,v (no h1 LDS, no per-pair
// barriers). 8 waves/block, 2 waves/SIMD; each wave = 2 pairs, colsum in regs.

typedef float f32x4 __attribute__((ext_vector_type(4)));
typedef short short8 __attribute__((ext_vector_type(8)));

__device__ __forceinline__ short bf16_rne(float f) {
    union { float f; uint32_t u; } v; v.f = f;
    uint32_t u = v.u + 0x7FFFu + ((v.u >> 16) & 1u);
    return (short)(u >> 16);
}

__device__ __forceinline__ uint32_t cvt_pk_bf16(float lo, float hi) {
    uint32_t r;
    asm("v_cvt_pk_bf16_f32 %0, %1, %2" : "=v"(r) : "v"(lo), "v"(hi));
    return r;
}

// K1: conv 8x8 stride 8 + relu + coord channels -> x[b][pos][26]
__global__ void k1_conv(const float* __restrict__ img, const float* __restrict__ cw,
                        const float* __restrict__ cb, float* __restrict__ x) {
    int b = blockIdx.x >> 2;
    int q = blockIdx.x & 3;
    for (int idx = q * 416 + threadIdx.x; idx < q * 416 + 416; idx += 256) {
        int pos = idx / 26;
        int ch  = idx - pos * 26;
        int r = pos >> 3, c = pos & 7;
        float val;
        if (ch < 24) {
            float s = cb[ch];
            #pragma unroll
            for (int ci = 0; ci < 3; ++ci)
                #pragma unroll
                for (int kr = 0; kr < 8; ++kr) {
                    const float* ip = img + ((b * 3 + ci) * 64 + r * 8 + kr) * 64 + c * 8;
                    const float* wp = cw + ((ch * 3 + ci) * 8 + kr) * 8;
                    #pragma unroll
                    for (int kc = 0; kc < 8; ++kc) s += ip[kc] * wp[kc];
                }
            val = fmaxf(s, 0.f);
        } else if (ch == 24) {
            val = -1.f + (2.f / 7.f) * (float)c;
        } else {
            val = -1.f + (2.f / 7.f) * (float)r;
        }
        x[(b * 64 + pos) * 26 + ch] = val;
    }
}

// K2: u'[bj][c] = x[bj]@W1[:26] + b1  (uv=0);  v[bj][c] = x[bj]@W1[26:]  (uv=1)
__global__ void k2_uv(const float* __restrict__ x, const float* __restrict__ w1,
                      const float* __restrict__ b1, float* __restrict__ u,
                      float* __restrict__ v) {
    int bj = blockIdx.x & 4095;
    int uv = blockIdx.x >> 12;
    int c = threadIdx.x;
    const float* xr = x + bj * 26;
    const float* w  = w1 + uv * 26 * 256;
    float s = uv ? 0.f : b1[c];
    #pragma unroll
    for (int k = 0; k < 26; ++k) s += xr[k] * w[k * 256 + c];
    (uv ? v : u)[bj * 256 + c] = s;
}

// K2b: pre-fragment W2 for MFMA B-operand, fragment-major:
// w2f[(fi*64 + lane)*8 + e] = bf16(W2[k][n]),
//   fi = ks*16 + ni2,  k = ks*32 + (lane>>4)*8 + e,  n = ni2*16 + (lane&15)
__global__ void k2b_w2f(const float* __restrict__ w2, short* __restrict__ w2f) {
    int fi = blockIdx.x;       // 0..127
    int l  = threadIdx.x;      // 0..63
    int ks = fi >> 4, ni2 = fi & 15;
    int n  = ni2 * 16 + (l & 15);
    int k0 = ks * 32 + (l >> 4) * 8;
    float f[8];
    #pragma unroll
    for (int e = 0; e < 8; ++e) f[e] = w2[(k0 + e) * 256 + n];
    union { short8 s; uint32_t w[4]; } A;
    A.w[0] = cvt_pk_bf16(f[0], f[1]);
    A.w[1] = cvt_pk_bf16(f[2], f[3]);
    A.w[2] = cvt_pk_bf16(f[4], f[5]);
    A.w[3] = cvt_pk_bf16(f[6], f[7]);
    *(short8*)(w2f + (fi * 64 + l) * 8) = A.s;
}

// K3: 256 blocks x 512 threads. W2 fragments in LDS (128 KB). Each wave handles
// 2 pairs (b,i): builds A-frags in regs from u,v; 64x256 GEMM vs LDS W2;
// relu+bias column-sum accumulated in regs; one flush -> part[wid][256].
__global__ __launch_bounds__(512, 2) void k3_pairs(
        const float* __restrict__ u, const float* __restrict__ v,
        const short* __restrict__ w2f, const float* __restrict__ b2,
        float* __restrict__ part) {
    __shared__ short8 w2s[8192];   // 128 KB, fragment-major
    int t = threadIdx.x;
    {
        const short8* src = (const short8*)w2f;
        #pragma unroll
        for (int it = 0; it < 16; ++it)
            w2s[it * 512 + t] = src[it * 512 + t];
    }
    __syncthreads();

    int lane = t & 63, wv = t >> 6;
    int lr = lane & 15, lg = lane >> 4;
    int wid = blockIdx.x * 8 + wv;          // 0..2047

    float csum[16];
    #pragma unroll
    for (int c = 0; c < 16; ++c) csum[c] = 0.f;

    #pragma unroll 1
    for (int q = 0; q < 2; ++q) {
        int unit = wid * 2 + q;             // 0..4095
        int b = unit >> 6, i = unit & 63;
        const float* up = u + (b * 64) * 256;
        const float* vp = v + (b * 64 + i) * 256;

        #pragma unroll 1
        for (int nh = 0; nh < 2; ++nh) {
            f32x4 acc[4][8];
            #pragma unroll
            for (int mi = 0; mi < 4; ++mi)
                #pragma unroll
                for (int ni = 0; ni < 8; ++ni) acc[mi][ni] = (f32x4){0.f, 0.f, 0.f, 0.f};

            #pragma unroll 1
            for (int kc = 0; kc < 2; ++kc) {
                short8 a[4][4];
                #pragma unroll
                for (int ksl = 0; ksl < 4; ++ksl) {
                    int k0 = (kc * 4 + ksl) * 32 + lg * 8;
                    float4 v0 = *(const float4*)(vp + k0);
                    float4 v1 = *(const float4*)(vp + k0 + 4);
                    #pragma unroll
                    for (int mi = 0; mi < 4; ++mi) {
                        const float* uu = up + (mi * 16 + lr) * 256 + k0;
                        float4 u0 = *(const float4*)(uu);
                        float4 u1 = *(const float4*)(uu + 4);
                        union { short8 s; uint32_t w[4]; } A;
                        A.w[0] = cvt_pk_bf16(fmaxf(u0.x + v0.x, 0.f),
                                             fmaxf(u0.y + v0.y, 0.f));
                        A.w[1] = cvt_pk_bf16(fmaxf(u0.z + v0.z, 0.f),
                                             fmaxf(u0.w + v0.w, 0.f));
                        A.w[2] = cvt_pk_bf16(fmaxf(u1.x + v1.x, 0.f),
                                             fmaxf(u1.y + v1.y, 0.f));
                        A.w[3] = cvt_pk_bf16(fmaxf(u1.z + v1.z, 0.f),
                                             fmaxf(u1.w + v1.w, 0.f));
                        a[mi][ksl] = A.s;
                    }
                }
                #pragma unroll
                for (int ksl = 0; ksl < 4; ++ksl) {
                    int ks = kc * 4 + ksl;
                    #pragma unroll
                    for (int ni = 0; ni < 8; ++ni) {
                        short8 Bf = w2s[(ks * 16 + nh * 8 + ni) * 64 + lane];
                        #pragma unroll
                        for (int mi = 0; mi < 4; ++mi)
                            acc[mi][ni] = __builtin_amdgcn_mfma_f32_16x16x32_bf16(
                                a[mi][ksl], Bf, acc[mi][ni], 0, 0, 0);
                    }
                }
            }
            // epilogue: relu(C + b2) partial column-sum (this lane's lg rows)
            #pragma unroll
            for (int ni = 0; ni < 8; ++ni) {
                float bias = b2[(nh * 8 + ni) * 16 + lr];
                float s = 0.f;
                #pragma unroll
                for (int mi = 0; mi < 4; ++mi)
                    #pragma unroll
                    for (int r = 0; r < 4; ++r)
                        s += fmaxf(acc[mi][ni][r] + bias, 0.f);
                csum[nh * 8 + ni] += s;
            }
        }
    }

    // flush: reduce over lg groups, lanes 0-15 store
    #pragma unroll
    for (int c = 0; c < 16; ++c) {
        float s = csum[c];
        s += __shfl_xor(s, 16);
        s += __shfl_xor(s, 32);
        if (lane < 16) part[wid * 256 + c * 16 + lr] = s;
    }
}

// K4: pooled[b][c] = sum over the 32 waves that handled b
__global__ void k4_pool(const float* __restrict__ part, float* __restrict__ pooled) {
    int b = blockIdx.x, c = threadIdx.x;
    float s = 0.f;
    #pragma unroll 4
    for (int w = 0; w < 32; ++w) s += part[(b * 32 + w) * 256 + c];
    pooled[b * 256 + c] = s;
}

// K5: f-head
__global__ void k5_head(const float* __restrict__ pooled, const float* __restrict__ fw1,
                        const float* __restrict__ fb1, const float* __restrict__ fw2,
                        const float* __restrict__ fb2, float* __restrict__ out) {
    __shared__ float P[256];
    __shared__ float wsum[4];
    int b = blockIdx.x, t = threadIdx.x;
    P[t] = pooled[b * 256 + t];
    __syncthreads();
    float s = fb1[t];
    for (int k = 0; k < 256; ++k) s += P[k] * fw1[k * 256 + t];
    float h = fmaxf(s, 0.f);
    float p = h * fw2[t];
    #pragma unroll
    for (int off = 32; off >= 1; off >>= 1) p += __shfl_xor(p, off);
    if ((t & 63) == 0) wsum[t >> 6] = p;
    __syncthreads();
    if (t == 0) out[b] = wsum[0] + wsum[1] + wsum[2] + wsum[3] + fb2[0];
}

extern "C" void kernel_launch(void* const* d_in, const int* in_sizes, int n_in,
                              void* d_out, int out_size, void* d_ws, size_t ws_size,
                              hipStream_t stream) {
    const float* image  = (const float*)d_in[0];
    const float* conv_w = (const float*)d_in[1];
    const float* conv_b = (const float*)d_in[2];
    const float* g_w1   = (const float*)d_in[3];
    const float* g_b1   = (const float*)d_in[4];
    const float* g_w2   = (const float*)d_in[5];
    const float* g_b2   = (const float*)d_in[6];
    const float* f_w1   = (const float*)d_in[7];
    const float* f_b1   = (const float*)d_in[8];
    const float* f_w2   = (const float*)d_in[9];
    const float* f_b2   = (const float*)d_in[10];
    float* out = (float*)d_out;

    char* ws = (char*)d_ws;
    float* x      = (float*)(ws + 0);          //  425984 B
    float* u      = (float*)(ws + 425984);     //  4 MB
    float* v      = (float*)(ws + 4620288);    //  4 MB
    short* w2f    = (short*)(ws + 8814592);    //  128 KB
    float* part   = (float*)(ws + 8945664);    //  2048*256*4 = 2 MB
    float* pooled = (float*)(ws + 11042816);   //  64 KB

    k1_conv<<<256, 256, 0, stream>>>(image, conv_w, conv_b, x);
    k2_uv <<<8192, 256, 0, stream>>>(x, g_w1, g_b1, u, v);
    k2b_w2f<<<128, 64, 0, stream>>>(g_w2, w2f);
    k3_pairs<<<256, 512, 0, stream>>>(u, v, w2f, g_b2, part);
    k4_pool<<<64, 256, 0, stream>>>(part, pooled);
    k5_head<<<64, 256, 0, stream>>>(pooled, f_w1, f_b1, f_w2, f_b2, out);
}